// Round 1
// 220.657 us; speedup vs baseline: 1.5732x; 1.5732x over previous
//
#include <hip/hip_runtime.h>
#include <hip/hip_bf16.h>

#define NCAT 72
#define DIM 32
#define BNUM 4
#define TEMP_INV (1.0f / 0.07f)
#define SEG_W 10.0f

// ws layout (floats):
#define WS_SUMS 0        // [4][72][32]
#define WS_CNTS 9216     // [4][72]
#define WS_PROT 9504     // [4][72][32]  normalized prototypes
#define WS_PRES 18720    // [4][72]      present mask as float
#define WS_LOSS 19008    // [4]
#define WS_KEEP 19012    // [4]
#define WS_TOTAL 19016

__device__ __forceinline__ bool is_missing(int c) {
    return (c == 13) | (c == 53) | (c == 61);
}

// k_accum v2.
// Diagnosis from rocprof: v1 was bound by LDS f32 scatter-atomics
// (~173 cyc per 64-lane ds_add_f32 -> per-lane RMW serialization; VALU 6.7%,
// HBM 5%, 444K cyc/CU all consistent). v2 removes wave-wide atomics:
//  - per-wave PRIVATE accumulators (no cross-wave races), 38KB LDS/block
//  - the 8 point-slots of a wave commit via 8 exec-masked plain float4
//    read-add-write steps (8 lanes, bank-conflict-free); same-label points
//    are ordered by the in-order LDS pipe across steps.
//  - sched_barrier(0) between steps: the guarded blocks are mutually
//    exclusive per-thread, so the compiler could otherwise legally fuse
//    them into ONE full-wave RMW, re-creating the same-address race.
//  - global loads software-pipelined (prefetch next chunk before commit).
template <int BPB>
__global__ __launch_bounds__(256) void k_accum(const float* __restrict__ emb,
                                               const int* __restrict__ lab,
                                               float* __restrict__ ws, int Nb) {
    __shared__ float s_acc[4][NCAT][DIM];  // per-wave private, rows 128B-aligned
    __shared__ float s_cnt[4][NCAT];
    const int t = threadIdx.x;
    const int b = blockIdx.x / BPB;
    const int blk = blockIdx.x % BPB;
    const int w = t >> 6;         // wave 0..3
    const int g = (t >> 3) & 7;   // point-slot within wave
    const int sub = t & 7;        // float4 index within point
    const int pofs = t >> 3;      // 0..31: point slot within block

    for (int i = t; i < 4 * NCAT * DIM; i += 256) ((float*)s_acc)[i] = 0.f;
    for (int i = t; i < 4 * NCAT; i += 256) ((float*)s_cnt)[i] = 0.f;
    __syncthreads();

    float* accw = &s_acc[w][0][0];
    const float* eb = emb + (size_t)b * Nb * DIM;
    const int* lb = lab + (size_t)b * Nb;

    // prologue of the software pipeline (first chunk always in range)
    int p = blk * 32 + pofs;
    int l_cur = lb[p];
    float4 v_cur = ((const float4*)(eb + (size_t)p * DIM))[sub];

    for (int p0 = blk * 32; p0 < Nb; p0 += BPB * 32) {
        // prefetch next chunk while this one computes/commits
        const int pn = p0 + BPB * 32 + pofs;
        int l_nxt = -1;
        float4 v_nxt = make_float4(0.f, 0.f, 0.f, 0.f);
        if (pn < Nb) {
            l_nxt = lb[pn];
            v_nxt = ((const float4*)(eb + (size_t)pn * DIM))[sub];
        }

        float ss = v_cur.x * v_cur.x + v_cur.y * v_cur.y +
                   v_cur.z * v_cur.z + v_cur.w * v_cur.w;
        ss += __shfl_xor(ss, 1);
        ss += __shfl_xor(ss, 2);
        ss += __shfl_xor(ss, 4);
        const float inv = 1.0f / fmaxf(sqrtf(ss), 1e-12f);
        const bool valid = (l_cur >= 0);
        const int lc = min(max(l_cur, 0), NCAT - 1);
        float4 u;
        u.x = v_cur.x * inv; u.y = v_cur.y * inv;
        u.z = v_cur.z * inv; u.w = v_cur.w * inv;

        // counts: one 8-lane ds_add per iteration (cheap even at per-lane rate)
        if (valid && sub == 0) unsafeAtomicAdd(&s_cnt[w][lc], 1.0f);

        float* rowp = accw + lc * DIM + sub * 4;
        #pragma unroll
        for (int k = 0; k < 8; k++) {
            if (g == k && valid) {
                float4* r4 = (float4*)rowp;
                float4 o = *r4;
                o.x += u.x; o.y += u.y; o.z += u.z; o.w += u.w;
                *r4 = o;
            }
            __builtin_amdgcn_sched_barrier(0);  // keep the 8 steps distinct & ordered
        }

        l_cur = l_nxt;
        v_cur = v_nxt;
    }
    __syncthreads();

    // flush: reduce 4 wave-copies, one global atomic per element
    float* gs = ws + WS_SUMS + b * NCAT * DIM;
    const float* sa = (const float*)s_acc;
    for (int i = t; i < NCAT * DIM; i += 256) {
        float val = sa[i] + sa[NCAT * DIM + i] +
                    sa[2 * NCAT * DIM + i] + sa[3 * NCAT * DIM + i];
        if (val != 0.f) unsafeAtomicAdd(&gs[i], val);
    }
    if (t < NCAT) {
        float c = s_cnt[0][t] + s_cnt[1][t] + s_cnt[2][t] + s_cnt[3][t];
        if (c != 0.f) unsafeAtomicAdd(ws + WS_CNTS + b * NCAT + t, c);
    }
}

// One block per batch: normalize sums -> prototypes in global ws.
__global__ __launch_bounds__(256) void k_proto(float* __restrict__ ws) {
    const int b = blockIdx.x;
    const float* gs = ws + WS_SUMS + b * NCAT * DIM;
    const float* gc = ws + WS_CNTS + b * NCAT;
    float* gp = ws + WS_PROT + b * NCAT * DIM;
    float* gpr = ws + WS_PRES + b * NCAT;
    const int dd = threadIdx.x & 31;
    const int r0 = threadIdx.x >> 5;
    for (int c = r0; c < NCAT; c += 8) {
        float cnt = gc[c];
        float val = gs[c * DIM + dd] / fmaxf(cnt, 1.0f);
        float ss = val * val;
        #pragma unroll
        for (int m = 16; m >= 1; m >>= 1) ss += __shfl_xor(ss, m);
        float inv = 1.0f / fmaxf(sqrtf(ss), 1e-12f);
        gp[c * DIM + dd] = val * inv;
        if (dd == 0) gpr[c] = (cnt > 0.f && !is_missing(c)) ? 1.0f : 0.0f;
    }
}

template <int BPB>
__global__ __launch_bounds__(256) void k_loss(const float* __restrict__ emb,
                                              const int* __restrict__ lab,
                                              const float* __restrict__ protos,
                                              const float* __restrict__ pres,
                                              float* __restrict__ lossout,
                                              int Nb) {
    __shared__ float s_red[8];
    const int b = blockIdx.x / BPB;
    const int blk = blockIdx.x % BPB;
    const int t = threadIdx.x;
    const float* pp = protos + b * NCAT * DIM;   // wave-uniform reads -> scalar path
    const float* pr = pres + b * NCAT;

    const float* eb = emb + (size_t)b * Nb * DIM;
    const int* lb = lab + (size_t)b * Nb;
    float acc = 0.f, kacc = 0.f;

    for (int i = blk * 256 + t; i < Nb; i += BPB * 256) {
        const int l = lb[i];
        const int lc = min(max(l, 0), NCAT - 1);
        float4 e[8];
        const float4* ep = (const float4*)(eb + (size_t)i * DIM);
        #pragma unroll
        for (int j = 0; j < 8; j++) e[j] = ep[j];
        float ss = 0.f;
        #pragma unroll
        for (int j = 0; j < 8; j++)
            ss += e[j].x * e[j].x + e[j].y * e[j].y + e[j].z * e[j].z + e[j].w * e[j].w;
        const float sca = TEMP_INV / fmaxf(sqrtf(ss), 1e-12f);

        float sum = 0.f, slab = 0.f;
        // |s| <= 1/T ~= 14.3 -> exp safe in fp32 without max-subtraction
        #pragma unroll 2
        for (int c = 0; c < NCAT; c++) {
            const float4* q4 = (const float4*)(pp + c * DIM);
            float d = 0.f;
            #pragma unroll
            for (int j = 0; j < 8; j++) {
                float4 q = q4[j];
                d += q.x * e[j].x + q.y * e[j].y + q.z * e[j].z + q.w * e[j].w;
            }
            const float s = d * sca;
            sum += pr[c] * __expf(s);
            if (c == lc) slab = s;
        }
        const bool keep = (l >= 0) && !is_missing(lc);
        if (keep) {
            acc += __logf(sum) - slab;
            kacc += 1.f;
        }
    }

    #pragma unroll
    for (int m = 32; m >= 1; m >>= 1) {
        acc += __shfl_xor(acc, m);
        kacc += __shfl_xor(kacc, m);
    }
    if ((t & 63) == 0) {
        s_red[t >> 6] = acc;
        s_red[4 + (t >> 6)] = kacc;
    }
    __syncthreads();
    if (t == 0) {
        float a = s_red[0] + s_red[1] + s_red[2] + s_red[3];
        float k = s_red[4] + s_red[5] + s_red[6] + s_red[7];
        unsafeAtomicAdd(lossout + b, a);            // WS_LOSS
        unsafeAtomicAdd(lossout + BNUM + b, k);     // WS_KEEP
    }
}

__global__ void k_final(const float* __restrict__ ws, float* __restrict__ out) {
    if (threadIdx.x == 0 && blockIdx.x == 0) {
        float s = 0.f;
        for (int b = 0; b < BNUM; b++) {
            float l = ws[WS_LOSS + b];
            float k = ws[WS_KEEP + b];
            s += l / fmaxf(k, 1.0f);
        }
        out[0] = SEG_W * (s / BNUM);
    }
}

extern "C" void kernel_launch(void* const* d_in, const int* in_sizes, int n_in,
                              void* d_out, int out_size, void* d_ws, size_t ws_size,
                              hipStream_t stream) {
    const float* emb = (const float*)d_in[0];
    const int* lab = (const int*)d_in[1];
    float* ws = (float*)d_ws;
    float* out = (float*)d_out;
    const int total_pts = in_sizes[1];
    const int Nb = total_pts / BNUM;

    hipMemsetAsync(d_ws, 0, WS_TOTAL * sizeof(float), stream);
    constexpr int BPB_ACC = 256;   // 1024 blocks -> 4 blocks/CU (LDS 38KB/block caps at 4)
    constexpr int BPB_LOSS = 512;  // 2048 blocks -> 8 blocks/CU
    k_accum<BPB_ACC><<<dim3(BNUM * BPB_ACC), dim3(256), 0, stream>>>(emb, lab, ws, Nb);
    k_proto<<<dim3(BNUM), dim3(256), 0, stream>>>(ws);
    k_loss<BPB_LOSS><<<dim3(BNUM * BPB_LOSS), dim3(256), 0, stream>>>(
        emb, lab, ws + WS_PROT, ws + WS_PRES, ws + WS_LOSS, Nb);
    k_final<<<1, 64, 0, stream>>>(ws, out);
}

// Round 2
// 168.683 us; speedup vs baseline: 2.0579x; 1.3081x over previous
//
#include <hip/hip_runtime.h>
#include <hip/hip_bf16.h>

#define NCAT 72
#define DIM 32
#define BNUM 4
#define TEMP_INV (1.0f / 0.07f)
#define SEG_W 10.0f

// ws layout (floats):
#define WS_SUMS 0        // [4][72][32]
#define WS_CNTS 9216     // [4][72]
#define WS_PROT 9504     // [4][72][32]  normalized prototypes
#define WS_PRES 18720    // [4][72]      present mask as float
#define WS_LOSS 19008    // [4]
#define WS_KEEP 19012    // [4]
#define WS_TOTAL 19016

__device__ __forceinline__ bool is_missing(int c) {
    return (c == 13) | (c == 53) | (c == 61);
}

// k_accum v2 (R1: LDS-atomic serialization fixed; ~45us, HBM floor ~22us).
template <int BPB>
__global__ __launch_bounds__(256) void k_accum(const float* __restrict__ emb,
                                               const int* __restrict__ lab,
                                               float* __restrict__ ws, int Nb) {
    __shared__ float s_acc[4][NCAT][DIM];  // per-wave private, rows 128B-aligned
    __shared__ float s_cnt[4][NCAT];
    const int t = threadIdx.x;
    const int b = blockIdx.x / BPB;
    const int blk = blockIdx.x % BPB;
    const int w = t >> 6;         // wave 0..3
    const int g = (t >> 3) & 7;   // point-slot within wave
    const int sub = t & 7;        // float4 index within point
    const int pofs = t >> 3;      // 0..31: point slot within block

    for (int i = t; i < 4 * NCAT * DIM; i += 256) ((float*)s_acc)[i] = 0.f;
    for (int i = t; i < 4 * NCAT; i += 256) ((float*)s_cnt)[i] = 0.f;
    __syncthreads();

    float* accw = &s_acc[w][0][0];
    const float* eb = emb + (size_t)b * Nb * DIM;
    const int* lb = lab + (size_t)b * Nb;

    // prologue of the software pipeline (first chunk always in range)
    int p = blk * 32 + pofs;
    int l_cur = lb[p];
    float4 v_cur = ((const float4*)(eb + (size_t)p * DIM))[sub];

    for (int p0 = blk * 32; p0 < Nb; p0 += BPB * 32) {
        // prefetch next chunk while this one computes/commits
        const int pn = p0 + BPB * 32 + pofs;
        int l_nxt = -1;
        float4 v_nxt = make_float4(0.f, 0.f, 0.f, 0.f);
        if (pn < Nb) {
            l_nxt = lb[pn];
            v_nxt = ((const float4*)(eb + (size_t)pn * DIM))[sub];
        }

        float ss = v_cur.x * v_cur.x + v_cur.y * v_cur.y +
                   v_cur.z * v_cur.z + v_cur.w * v_cur.w;
        ss += __shfl_xor(ss, 1);
        ss += __shfl_xor(ss, 2);
        ss += __shfl_xor(ss, 4);
        const float inv = 1.0f / fmaxf(sqrtf(ss), 1e-12f);
        const bool valid = (l_cur >= 0);
        const int lc = min(max(l_cur, 0), NCAT - 1);
        float4 u;
        u.x = v_cur.x * inv; u.y = v_cur.y * inv;
        u.z = v_cur.z * inv; u.w = v_cur.w * inv;

        // counts: one 8-lane ds_add per iteration (cheap even at per-lane rate)
        if (valid && sub == 0) unsafeAtomicAdd(&s_cnt[w][lc], 1.0f);

        float* rowp = accw + lc * DIM + sub * 4;
        #pragma unroll
        for (int k = 0; k < 8; k++) {
            if (g == k && valid) {
                float4* r4 = (float4*)rowp;
                float4 o = *r4;
                o.x += u.x; o.y += u.y; o.z += u.z; o.w += u.w;
                *r4 = o;
            }
            __builtin_amdgcn_sched_barrier(0);  // keep the 8 steps distinct & ordered
        }

        l_cur = l_nxt;
        v_cur = v_nxt;
    }
    __syncthreads();

    // flush: reduce 4 wave-copies, one global atomic per element
    float* gs = ws + WS_SUMS + b * NCAT * DIM;
    const float* sa = (const float*)s_acc;
    for (int i = t; i < NCAT * DIM; i += 256) {
        float val = sa[i] + sa[NCAT * DIM + i] +
                    sa[2 * NCAT * DIM + i] + sa[3 * NCAT * DIM + i];
        if (val != 0.f) unsafeAtomicAdd(&gs[i], val);
    }
    if (t < NCAT) {
        float c = s_cnt[0][t] + s_cnt[1][t] + s_cnt[2][t] + s_cnt[3][t];
        if (c != 0.f) unsafeAtomicAdd(ws + WS_CNTS + b * NCAT + t, c);
    }
}

// One block per batch: normalize sums -> prototypes in global ws.
__global__ __launch_bounds__(256) void k_proto(float* __restrict__ ws) {
    const int b = blockIdx.x;
    const float* gs = ws + WS_SUMS + b * NCAT * DIM;
    const float* gc = ws + WS_CNTS + b * NCAT;
    float* gp = ws + WS_PROT + b * NCAT * DIM;
    float* gpr = ws + WS_PRES + b * NCAT;
    const int dd = threadIdx.x & 31;
    const int r0 = threadIdx.x >> 5;
    for (int c = r0; c < NCAT; c += 8) {
        float cnt = gc[c];
        float val = gs[c * DIM + dd] / fmaxf(cnt, 1.0f);
        float ss = val * val;
        #pragma unroll
        for (int m = 16; m >= 1; m >>= 1) ss += __shfl_xor(ss, m);
        float inv = 1.0f / fmaxf(sqrtf(ss), 1e-12f);
        gp[c * DIM + dd] = val * inv;
        if (dd == 0) gpr[c] = (cnt > 0.f && !is_missing(c)) ? 1.0f : 0.0f;
    }
}

// k_loss v2.
// R1 diagnosis: VGPR_Count=32 forced occupancy-driven spilling -- the
// float4 e[8] (32 VGPRs) could not stay resident across the 72-category
// loop, inflating VALU instructions ~3.6x over the 2304-FMA/point floor
// (165us vs ~40us). Fix: __launch_bounds__(256,4) -> 128-VGPR budget,
// named e0..e7 scalars, explicit fmaf chains; prototype reads stay
// wave-uniform (SGPR-streamed, 1 SGPR operand/VALU is free).
template <int BPB>
__global__ __launch_bounds__(256, 4) void k_loss(const float* __restrict__ emb,
                                                 const int* __restrict__ lab,
                                                 const float* __restrict__ protos,
                                                 const float* __restrict__ pres,
                                                 float* __restrict__ lossout,
                                                 int Nb) {
    __shared__ float s_red[8];
    const int b = blockIdx.x / BPB;
    const int blk = blockIdx.x % BPB;
    const int t = threadIdx.x;
    const float* pp = protos + b * NCAT * DIM;   // wave-uniform reads -> scalar path
    const float* pr = pres + b * NCAT;

    const float* eb = emb + (size_t)b * Nb * DIM;
    const int* lb = lab + (size_t)b * Nb;
    float acc = 0.f, kacc = 0.f;

    for (int i = blk * 256 + t; i < Nb; i += BPB * 256) {
        const int l = lb[i];
        const int lc = min(max(l, 0), NCAT - 1);
        const float4* ep = (const float4*)(eb + (size_t)i * DIM);
        float4 e0 = ep[0], e1 = ep[1], e2 = ep[2], e3 = ep[3];
        float4 e4 = ep[4], e5 = ep[5], e6 = ep[6], e7 = ep[7];

        float ss = 0.f;
        ss = fmaf(e0.x, e0.x, ss); ss = fmaf(e0.y, e0.y, ss); ss = fmaf(e0.z, e0.z, ss); ss = fmaf(e0.w, e0.w, ss);
        ss = fmaf(e1.x, e1.x, ss); ss = fmaf(e1.y, e1.y, ss); ss = fmaf(e1.z, e1.z, ss); ss = fmaf(e1.w, e1.w, ss);
        ss = fmaf(e2.x, e2.x, ss); ss = fmaf(e2.y, e2.y, ss); ss = fmaf(e2.z, e2.z, ss); ss = fmaf(e2.w, e2.w, ss);
        ss = fmaf(e3.x, e3.x, ss); ss = fmaf(e3.y, e3.y, ss); ss = fmaf(e3.z, e3.z, ss); ss = fmaf(e3.w, e3.w, ss);
        ss = fmaf(e4.x, e4.x, ss); ss = fmaf(e4.y, e4.y, ss); ss = fmaf(e4.z, e4.z, ss); ss = fmaf(e4.w, e4.w, ss);
        ss = fmaf(e5.x, e5.x, ss); ss = fmaf(e5.y, e5.y, ss); ss = fmaf(e5.z, e5.z, ss); ss = fmaf(e5.w, e5.w, ss);
        ss = fmaf(e6.x, e6.x, ss); ss = fmaf(e6.y, e6.y, ss); ss = fmaf(e6.z, e6.z, ss); ss = fmaf(e6.w, e6.w, ss);
        ss = fmaf(e7.x, e7.x, ss); ss = fmaf(e7.y, e7.y, ss); ss = fmaf(e7.z, e7.z, ss); ss = fmaf(e7.w, e7.w, ss);
        const float sca = TEMP_INV / fmaxf(sqrtf(ss), 1e-12f);

        float sum = 0.f, slab = 0.f;
        // |s| <= 1/T ~= 14.3 -> exp safe in fp32 without max-subtraction
        #pragma unroll 2
        for (int c = 0; c < NCAT; c++) {
            const float4* q4 = (const float4*)(pp + c * DIM);
            float d = 0.f;
            {
                float4 q = q4[0];
                d = fmaf(q.x, e0.x, d); d = fmaf(q.y, e0.y, d); d = fmaf(q.z, e0.z, d); d = fmaf(q.w, e0.w, d);
            }
            {
                float4 q = q4[1];
                d = fmaf(q.x, e1.x, d); d = fmaf(q.y, e1.y, d); d = fmaf(q.z, e1.z, d); d = fmaf(q.w, e1.w, d);
            }
            {
                float4 q = q4[2];
                d = fmaf(q.x, e2.x, d); d = fmaf(q.y, e2.y, d); d = fmaf(q.z, e2.z, d); d = fmaf(q.w, e2.w, d);
            }
            {
                float4 q = q4[3];
                d = fmaf(q.x, e3.x, d); d = fmaf(q.y, e3.y, d); d = fmaf(q.z, e3.z, d); d = fmaf(q.w, e3.w, d);
            }
            {
                float4 q = q4[4];
                d = fmaf(q.x, e4.x, d); d = fmaf(q.y, e4.y, d); d = fmaf(q.z, e4.z, d); d = fmaf(q.w, e4.w, d);
            }
            {
                float4 q = q4[5];
                d = fmaf(q.x, e5.x, d); d = fmaf(q.y, e5.y, d); d = fmaf(q.z, e5.z, d); d = fmaf(q.w, e5.w, d);
            }
            {
                float4 q = q4[6];
                d = fmaf(q.x, e6.x, d); d = fmaf(q.y, e6.y, d); d = fmaf(q.z, e6.z, d); d = fmaf(q.w, e6.w, d);
            }
            {
                float4 q = q4[7];
                d = fmaf(q.x, e7.x, d); d = fmaf(q.y, e7.y, d); d = fmaf(q.z, e7.z, d); d = fmaf(q.w, e7.w, d);
            }
            const float s = d * sca;
            sum += pr[c] * __expf(s);
            if (c == lc) slab = s;
        }
        const bool keep = (l >= 0) && !is_missing(lc);
        if (keep) {
            acc += __logf(sum) - slab;
            kacc += 1.f;
        }
    }

    #pragma unroll
    for (int m = 32; m >= 1; m >>= 1) {
        acc += __shfl_xor(acc, m);
        kacc += __shfl_xor(kacc, m);
    }
    if ((t & 63) == 0) {
        s_red[t >> 6] = acc;
        s_red[4 + (t >> 6)] = kacc;
    }
    __syncthreads();
    if (t == 0) {
        float a = s_red[0] + s_red[1] + s_red[2] + s_red[3];
        float k = s_red[4] + s_red[5] + s_red[6] + s_red[7];
        unsafeAtomicAdd(lossout + b, a);            // WS_LOSS
        unsafeAtomicAdd(lossout + BNUM + b, k);     // WS_KEEP
    }
}

__global__ void k_final(const float* __restrict__ ws, float* __restrict__ out) {
    if (threadIdx.x == 0 && blockIdx.x == 0) {
        float s = 0.f;
        for (int b = 0; b < BNUM; b++) {
            float l = ws[WS_LOSS + b];
            float k = ws[WS_KEEP + b];
            s += l / fmaxf(k, 1.0f);
        }
        out[0] = SEG_W * (s / BNUM);
    }
}

extern "C" void kernel_launch(void* const* d_in, const int* in_sizes, int n_in,
                              void* d_out, int out_size, void* d_ws, size_t ws_size,
                              hipStream_t stream) {
    const float* emb = (const float*)d_in[0];
    const int* lab = (const int*)d_in[1];
    float* ws = (float*)d_ws;
    float* out = (float*)d_out;
    const int total_pts = in_sizes[1];
    const int Nb = total_pts / BNUM;

    hipMemsetAsync(d_ws, 0, WS_TOTAL * sizeof(float), stream);
    constexpr int BPB_ACC = 256;   // 1024 blocks -> 4 blocks/CU (LDS 38KB/block caps at 4)
    constexpr int BPB_LOSS = 512;  // 2048 blocks -> 8 blocks/CU (2 passes at 4-resident)
    k_accum<BPB_ACC><<<dim3(BNUM * BPB_ACC), dim3(256), 0, stream>>>(emb, lab, ws, Nb);
    k_proto<<<dim3(BNUM), dim3(256), 0, stream>>>(ws);
    k_loss<BPB_LOSS><<<dim3(BNUM * BPB_LOSS), dim3(256), 0, stream>>>(
        emb, lab, ws + WS_PROT, ws + WS_PRES, ws + WS_LOSS, Nb);
    k_final<<<1, 64, 0, stream>>>(ws, out);
}

// Round 3
// 164.735 us; speedup vs baseline: 2.1073x; 1.0240x over previous
//
#include <hip/hip_runtime.h>
#include <hip/hip_bf16.h>

#define NCAT 72
#define DIM 32
#define BNUM 4
#define TEMP_INV (1.0f / 0.07f)
#define SEG_W 10.0f

// ws layout (floats):
#define WS_SUMS 0        // [4][72][32]
#define WS_CNTS 9216     // [4][72]
#define WS_PROT 9504     // [4][72][32]  normalized prototypes
#define WS_PRES 18720    // [4][72]      present mask as float
#define WS_LOSS 19008    // [4]
#define WS_KEEP 19012    // [4]
#define WS_TOTAL 19016

__device__ __forceinline__ bool is_missing(int c) {
    return (c == 13) | (c == 53) | (c == 61);
}

// k_accum v2 (R1: LDS-atomic serialization fixed).
template <int BPB>
__global__ __launch_bounds__(256) void k_accum(const float* __restrict__ emb,
                                               const int* __restrict__ lab,
                                               float* __restrict__ ws, int Nb) {
    __shared__ float s_acc[4][NCAT][DIM];  // per-wave private, rows 128B-aligned
    __shared__ float s_cnt[4][NCAT];
    const int t = threadIdx.x;
    const int b = blockIdx.x / BPB;
    const int blk = blockIdx.x % BPB;
    const int w = t >> 6;         // wave 0..3
    const int g = (t >> 3) & 7;   // point-slot within wave
    const int sub = t & 7;        // float4 index within point
    const int pofs = t >> 3;      // 0..31: point slot within block

    for (int i = t; i < 4 * NCAT * DIM; i += 256) ((float*)s_acc)[i] = 0.f;
    for (int i = t; i < 4 * NCAT; i += 256) ((float*)s_cnt)[i] = 0.f;
    __syncthreads();

    float* accw = &s_acc[w][0][0];
    const float* eb = emb + (size_t)b * Nb * DIM;
    const int* lb = lab + (size_t)b * Nb;

    // prologue of the software pipeline (first chunk always in range)
    int p = blk * 32 + pofs;
    int l_cur = lb[p];
    float4 v_cur = ((const float4*)(eb + (size_t)p * DIM))[sub];

    for (int p0 = blk * 32; p0 < Nb; p0 += BPB * 32) {
        // prefetch next chunk while this one computes/commits
        const int pn = p0 + BPB * 32 + pofs;
        int l_nxt = -1;
        float4 v_nxt = make_float4(0.f, 0.f, 0.f, 0.f);
        if (pn < Nb) {
            l_nxt = lb[pn];
            v_nxt = ((const float4*)(eb + (size_t)pn * DIM))[sub];
        }

        float ss = v_cur.x * v_cur.x + v_cur.y * v_cur.y +
                   v_cur.z * v_cur.z + v_cur.w * v_cur.w;
        ss += __shfl_xor(ss, 1);
        ss += __shfl_xor(ss, 2);
        ss += __shfl_xor(ss, 4);
        const float inv = 1.0f / fmaxf(sqrtf(ss), 1e-12f);
        const bool valid = (l_cur >= 0);
        const int lc = min(max(l_cur, 0), NCAT - 1);
        float4 u;
        u.x = v_cur.x * inv; u.y = v_cur.y * inv;
        u.z = v_cur.z * inv; u.w = v_cur.w * inv;

        // counts: one 8-lane ds_add per iteration (cheap even at per-lane rate)
        if (valid && sub == 0) unsafeAtomicAdd(&s_cnt[w][lc], 1.0f);

        float* rowp = accw + lc * DIM + sub * 4;
        #pragma unroll
        for (int k = 0; k < 8; k++) {
            if (g == k && valid) {
                float4* r4 = (float4*)rowp;
                float4 o = *r4;
                o.x += u.x; o.y += u.y; o.z += u.z; o.w += u.w;
                *r4 = o;
            }
            __builtin_amdgcn_sched_barrier(0);  // keep the 8 steps distinct & ordered
        }

        l_cur = l_nxt;
        v_cur = v_nxt;
    }
    __syncthreads();

    // flush: reduce 4 wave-copies, one global atomic per element
    float* gs = ws + WS_SUMS + b * NCAT * DIM;
    const float* sa = (const float*)s_acc;
    for (int i = t; i < NCAT * DIM; i += 256) {
        float val = sa[i] + sa[NCAT * DIM + i] +
                    sa[2 * NCAT * DIM + i] + sa[3 * NCAT * DIM + i];
        if (val != 0.f) unsafeAtomicAdd(&gs[i], val);
    }
    if (t < NCAT) {
        float c = s_cnt[0][t] + s_cnt[1][t] + s_cnt[2][t] + s_cnt[3][t];
        if (c != 0.f) unsafeAtomicAdd(ws + WS_CNTS + b * NCAT + t, c);
    }
}

// One block per batch: normalize sums -> prototypes in global ws.
__global__ __launch_bounds__(256) void k_proto(float* __restrict__ ws) {
    const int b = blockIdx.x;
    const float* gs = ws + WS_SUMS + b * NCAT * DIM;
    const float* gc = ws + WS_CNTS + b * NCAT;
    float* gp = ws + WS_PROT + b * NCAT * DIM;
    float* gpr = ws + WS_PRES + b * NCAT;
    const int dd = threadIdx.x & 31;
    const int r0 = threadIdx.x >> 5;
    for (int c = r0; c < NCAT; c += 8) {
        float cnt = gc[c];
        float val = gs[c * DIM + dd] / fmaxf(cnt, 1.0f);
        float ss = val * val;
        #pragma unroll
        for (int m = 16; m >= 1; m >>= 1) ss += __shfl_xor(ss, m);
        float inv = 1.0f / fmaxf(sqrtf(ss), 1e-12f);
        gp[c * DIM + dd] = val * inv;
        if (dd == 0) gpr[c] = (cnt > 0.f && !is_missing(c)) ? 1.0f : 0.0f;
    }
}

// k_loss v3.
// R2 diagnosis: VGPR_Count=28 -> allocator still refused residency for the
// 32-float embedding (launch_bounds caps regs, doesn't force use); VALU
// instr count 2.1x floor from in-loop re-fetch. Fixes:
//  (a) launder e through empty asm -> provenance hidden, reload impossible
//  (b) #pragma unroll 1 on the point loop (no x2 interleave pressure)
//  (c) fold TEMP_INV*log2e/||e|| into e once; inner loop = 32 fmac + exp2
//  (d) label logit via one extra 32-FMA dot outside the loop instead of
//      72x (v_cmp+v_cndmask)
#define KEEP4(v) asm volatile("" : "+v"(v.x), "+v"(v.y), "+v"(v.z), "+v"(v.w))

template <int BPB>
__global__ __launch_bounds__(256, 4) void k_loss(const float* __restrict__ emb,
                                                 const int* __restrict__ lab,
                                                 const float* __restrict__ protos,
                                                 const float* __restrict__ pres,
                                                 float* __restrict__ lossout,
                                                 int Nb) {
    __shared__ float s_red[8];
    const int b = blockIdx.x / BPB;
    const int blk = blockIdx.x % BPB;
    const int t = threadIdx.x;
    const float* pp = protos + b * NCAT * DIM;   // wave-uniform reads -> scalar path
    const float* pr = pres + b * NCAT;

    const float* eb = emb + (size_t)b * Nb * DIM;
    const int* lb = lab + (size_t)b * Nb;
    float acc = 0.f, kacc = 0.f;

    const float LOG2E = 1.4426950408889634f;
    const float LN2 = 0.6931471805599453f;

    #pragma unroll 1
    for (int i = blk * 256 + t; i < Nb; i += BPB * 256) {
        const int l = lb[i];
        const int lc = min(max(l, 0), NCAT - 1);
        const float4* ep = (const float4*)(eb + (size_t)i * DIM);
        float4 e0 = ep[0], e1 = ep[1], e2 = ep[2], e3 = ep[3];
        float4 e4 = ep[4], e5 = ep[5], e6 = ep[6], e7 = ep[7];

        float ss = 0.f;
        ss = fmaf(e0.x, e0.x, ss); ss = fmaf(e0.y, e0.y, ss); ss = fmaf(e0.z, e0.z, ss); ss = fmaf(e0.w, e0.w, ss);
        ss = fmaf(e1.x, e1.x, ss); ss = fmaf(e1.y, e1.y, ss); ss = fmaf(e1.z, e1.z, ss); ss = fmaf(e1.w, e1.w, ss);
        ss = fmaf(e2.x, e2.x, ss); ss = fmaf(e2.y, e2.y, ss); ss = fmaf(e2.z, e2.z, ss); ss = fmaf(e2.w, e2.w, ss);
        ss = fmaf(e3.x, e3.x, ss); ss = fmaf(e3.y, e3.y, ss); ss = fmaf(e3.z, e3.z, ss); ss = fmaf(e3.w, e3.w, ss);
        ss = fmaf(e4.x, e4.x, ss); ss = fmaf(e4.y, e4.y, ss); ss = fmaf(e4.z, e4.z, ss); ss = fmaf(e4.w, e4.w, ss);
        ss = fmaf(e5.x, e5.x, ss); ss = fmaf(e5.y, e5.y, ss); ss = fmaf(e5.z, e5.z, ss); ss = fmaf(e5.w, e5.w, ss);
        ss = fmaf(e6.x, e6.x, ss); ss = fmaf(e6.y, e6.y, ss); ss = fmaf(e6.z, e6.z, ss); ss = fmaf(e6.w, e6.w, ss);
        ss = fmaf(e7.x, e7.x, ss); ss = fmaf(e7.y, e7.y, ss); ss = fmaf(e7.z, e7.z, ss); ss = fmaf(e7.w, e7.w, ss);
        // fold temperature, log2(e) and the L2-norm into e itself
        const float sca = (TEMP_INV * LOG2E) / fmaxf(sqrtf(ss), 1e-12f);
        e0.x *= sca; e0.y *= sca; e0.z *= sca; e0.w *= sca;
        e1.x *= sca; e1.y *= sca; e1.z *= sca; e1.w *= sca;
        e2.x *= sca; e2.y *= sca; e2.z *= sca; e2.w *= sca;
        e3.x *= sca; e3.y *= sca; e3.z *= sca; e3.w *= sca;
        e4.x *= sca; e4.y *= sca; e4.z *= sca; e4.w *= sca;
        e5.x *= sca; e5.y *= sca; e5.z *= sca; e5.w *= sca;
        e6.x *= sca; e6.y *= sca; e6.z *= sca; e6.w *= sca;
        e7.x *= sca; e7.y *= sca; e7.z *= sca; e7.w *= sca;
        // launder: hide provenance so the c-loop cannot re-load e from memory
        KEEP4(e0); KEEP4(e1); KEEP4(e2); KEEP4(e3);
        KEEP4(e4); KEEP4(e5); KEEP4(e6); KEEP4(e7);

        // label logit (log2 space), hoisted out of the category loop
        float dlab = 0.f;
        {
            const float4* q4 = (const float4*)(pp + lc * DIM);
            float4 q;
            q = q4[0]; dlab = fmaf(q.x, e0.x, dlab); dlab = fmaf(q.y, e0.y, dlab); dlab = fmaf(q.z, e0.z, dlab); dlab = fmaf(q.w, e0.w, dlab);
            q = q4[1]; dlab = fmaf(q.x, e1.x, dlab); dlab = fmaf(q.y, e1.y, dlab); dlab = fmaf(q.z, e1.z, dlab); dlab = fmaf(q.w, e1.w, dlab);
            q = q4[2]; dlab = fmaf(q.x, e2.x, dlab); dlab = fmaf(q.y, e2.y, dlab); dlab = fmaf(q.z, e2.z, dlab); dlab = fmaf(q.w, e2.w, dlab);
            q = q4[3]; dlab = fmaf(q.x, e3.x, dlab); dlab = fmaf(q.y, e3.y, dlab); dlab = fmaf(q.z, e3.z, dlab); dlab = fmaf(q.w, e3.w, dlab);
            q = q4[4]; dlab = fmaf(q.x, e4.x, dlab); dlab = fmaf(q.y, e4.y, dlab); dlab = fmaf(q.z, e4.z, dlab); dlab = fmaf(q.w, e4.w, dlab);
            q = q4[5]; dlab = fmaf(q.x, e5.x, dlab); dlab = fmaf(q.y, e5.y, dlab); dlab = fmaf(q.z, e5.z, dlab); dlab = fmaf(q.w, e5.w, dlab);
            q = q4[6]; dlab = fmaf(q.x, e6.x, dlab); dlab = fmaf(q.y, e6.y, dlab); dlab = fmaf(q.z, e6.z, dlab); dlab = fmaf(q.w, e6.w, dlab);
            q = q4[7]; dlab = fmaf(q.x, e7.x, dlab); dlab = fmaf(q.y, e7.y, dlab); dlab = fmaf(q.z, e7.z, dlab); dlab = fmaf(q.w, e7.w, dlab);
        }

        float sum = 0.f;
        // d in log2 space, |d| <= 14.3*log2e ~ 20.6 -> exp2 safe in fp32
        #pragma unroll 2
        for (int c = 0; c < NCAT; c++) {
            const float4* q4 = (const float4*)(pp + c * DIM);
            float d = 0.f;
            {
                float4 q = q4[0];
                d = fmaf(q.x, e0.x, d); d = fmaf(q.y, e0.y, d); d = fmaf(q.z, e0.z, d); d = fmaf(q.w, e0.w, d);
            }
            {
                float4 q = q4[1];
                d = fmaf(q.x, e1.x, d); d = fmaf(q.y, e1.y, d); d = fmaf(q.z, e1.z, d); d = fmaf(q.w, e1.w, d);
            }
            {
                float4 q = q4[2];
                d = fmaf(q.x, e2.x, d); d = fmaf(q.y, e2.y, d); d = fmaf(q.z, e2.z, d); d = fmaf(q.w, e2.w, d);
            }
            {
                float4 q = q4[3];
                d = fmaf(q.x, e3.x, d); d = fmaf(q.y, e3.y, d); d = fmaf(q.z, e3.z, d); d = fmaf(q.w, e3.w, d);
            }
            {
                float4 q = q4[4];
                d = fmaf(q.x, e4.x, d); d = fmaf(q.y, e4.y, d); d = fmaf(q.z, e4.z, d); d = fmaf(q.w, e4.w, d);
            }
            {
                float4 q = q4[5];
                d = fmaf(q.x, e5.x, d); d = fmaf(q.y, e5.y, d); d = fmaf(q.z, e5.z, d); d = fmaf(q.w, e5.w, d);
            }
            {
                float4 q = q4[6];
                d = fmaf(q.x, e6.x, d); d = fmaf(q.y, e6.y, d); d = fmaf(q.z, e6.z, d); d = fmaf(q.w, e6.w, d);
            }
            {
                float4 q = q4[7];
                d = fmaf(q.x, e7.x, d); d = fmaf(q.y, e7.y, d); d = fmaf(q.z, e7.z, d); d = fmaf(q.w, e7.w, d);
            }
            sum = fmaf(pr[c], __builtin_amdgcn_exp2f(d), sum);
        }
        const bool keep = (l >= 0) && !is_missing(lc);
        if (keep) {
            // nll = ln(sum_e) - s_lab = ln2 * (log2(sum) - dlab)
            acc = fmaf(LN2, __builtin_amdgcn_logf(sum) - dlab, acc);
            kacc += 1.f;
        }
    }

    #pragma unroll
    for (int m = 32; m >= 1; m >>= 1) {
        acc += __shfl_xor(acc, m);
        kacc += __shfl_xor(kacc, m);
    }
    if ((t & 63) == 0) {
        s_red[t >> 6] = acc;
        s_red[4 + (t >> 6)] = kacc;
    }
    __syncthreads();
    if (t == 0) {
        float a = s_red[0] + s_red[1] + s_red[2] + s_red[3];
        float k = s_red[4] + s_red[5] + s_red[6] + s_red[7];
        unsafeAtomicAdd(lossout + b, a);            // WS_LOSS
        unsafeAtomicAdd(lossout + BNUM + b, k);     // WS_KEEP
    }
}

__global__ void k_final(const float* __restrict__ ws, float* __restrict__ out) {
    if (threadIdx.x == 0 && blockIdx.x == 0) {
        float s = 0.f;
        for (int b = 0; b < BNUM; b++) {
            float l = ws[WS_LOSS + b];
            float k = ws[WS_KEEP + b];
            s += l / fmaxf(k, 1.0f);
        }
        out[0] = SEG_W * (s / BNUM);
    }
}

extern "C" void kernel_launch(void* const* d_in, const int* in_sizes, int n_in,
                              void* d_out, int out_size, void* d_ws, size_t ws_size,
                              hipStream_t stream) {
    const float* emb = (const float*)d_in[0];
    const int* lab = (const int*)d_in[1];
    float* ws = (float*)d_ws;
    float* out = (float*)d_out;
    const int total_pts = in_sizes[1];
    const int Nb = total_pts / BNUM;

    hipMemsetAsync(d_ws, 0, WS_TOTAL * sizeof(float), stream);
    constexpr int BPB_ACC = 256;   // 1024 blocks -> 4 blocks/CU (LDS 38KB/block caps at 4)
    constexpr int BPB_LOSS = 512;  // 2048 blocks
    k_accum<BPB_ACC><<<dim3(BNUM * BPB_ACC), dim3(256), 0, stream>>>(emb, lab, ws, Nb);
    k_proto<<<dim3(BNUM), dim3(256), 0, stream>>>(ws);
    k_loss<BPB_LOSS><<<dim3(BNUM * BPB_LOSS), dim3(256), 0, stream>>>(
        emb, lab, ws + WS_PROT, ws + WS_PRES, ws + WS_LOSS, Nb);
    k_final<<<1, 64, 0, stream>>>(ws, out);
}

// Round 4
// 152.433 us; speedup vs baseline: 2.2773x; 1.0807x over previous
//
#include <hip/hip_runtime.h>
#include <hip/hip_bf16.h>

#define NCAT 72
#define NCATP 80          // padded to 5 MFMA n-tiles of 16
#define DIM 32
#define BNUM 4
#define TEMP_INV (1.0f / 0.07f)
#define SEG_W 10.0f

// ws layout (floats):
#define WS_SUMS 0         // [4][72][32]
#define WS_CNTS 9216      // [4][72]
#define WS_PROT 9504      // [4][80][32]  normalized prototypes, PADDED (rows 72..79 zero)
#define WS_PRES 19744     // [4][80]      present mask as float, PADDED
#define WS_LOSS 20064     // [4]
#define WS_KEEP 20068     // [4]
#define WS_TOTAL 20072

typedef __attribute__((ext_vector_type(8))) short short8v;   // 8 bf16
typedef __attribute__((ext_vector_type(4))) float f32x4;

__device__ __forceinline__ bool is_missing(int c) {
    return (c == 13) | (c == 53) | (c == 61);
}

// float -> bf16(RNE) bits, and the fp32 value of that bf16 (for lo-split)
__device__ __forceinline__ short f2bf_hi(float f, float* hi_f) {
    unsigned u = __float_as_uint(f);
    unsigned r = u + 0x7FFFu + ((u >> 16) & 1u);
    *hi_f = __uint_as_float(r & 0xFFFF0000u);
    return (short)(r >> 16);
}
__device__ __forceinline__ short f2bf(float f) {
    unsigned u = __float_as_uint(f);
    unsigned r = u + 0x7FFFu + ((u >> 16) & 1u);
    return (short)(r >> 16);
}

// k_accum v2 (R1: LDS-atomic serialization fixed).
template <int BPB>
__global__ __launch_bounds__(256) void k_accum(const float* __restrict__ emb,
                                               const int* __restrict__ lab,
                                               float* __restrict__ ws, int Nb) {
    __shared__ float s_acc[4][NCAT][DIM];  // per-wave private, rows 128B-aligned
    __shared__ float s_cnt[4][NCAT];
    const int t = threadIdx.x;
    const int b = blockIdx.x / BPB;
    const int blk = blockIdx.x % BPB;
    const int w = t >> 6;         // wave 0..3
    const int g = (t >> 3) & 7;   // point-slot within wave
    const int sub = t & 7;        // float4 index within point
    const int pofs = t >> 3;      // 0..31: point slot within block

    for (int i = t; i < 4 * NCAT * DIM; i += 256) ((float*)s_acc)[i] = 0.f;
    for (int i = t; i < 4 * NCAT; i += 256) ((float*)s_cnt)[i] = 0.f;
    __syncthreads();

    float* accw = &s_acc[w][0][0];
    const float* eb = emb + (size_t)b * Nb * DIM;
    const int* lb = lab + (size_t)b * Nb;

    int p = blk * 32 + pofs;
    int l_cur = lb[p];
    float4 v_cur = ((const float4*)(eb + (size_t)p * DIM))[sub];

    for (int p0 = blk * 32; p0 < Nb; p0 += BPB * 32) {
        const int pn = p0 + BPB * 32 + pofs;
        int l_nxt = -1;
        float4 v_nxt = make_float4(0.f, 0.f, 0.f, 0.f);
        if (pn < Nb) {
            l_nxt = lb[pn];
            v_nxt = ((const float4*)(eb + (size_t)pn * DIM))[sub];
        }

        float ss = v_cur.x * v_cur.x + v_cur.y * v_cur.y +
                   v_cur.z * v_cur.z + v_cur.w * v_cur.w;
        ss += __shfl_xor(ss, 1);
        ss += __shfl_xor(ss, 2);
        ss += __shfl_xor(ss, 4);
        const float inv = 1.0f / fmaxf(sqrtf(ss), 1e-12f);
        const bool valid = (l_cur >= 0);
        const int lc = min(max(l_cur, 0), NCAT - 1);
        float4 u;
        u.x = v_cur.x * inv; u.y = v_cur.y * inv;
        u.z = v_cur.z * inv; u.w = v_cur.w * inv;

        if (valid && sub == 0) unsafeAtomicAdd(&s_cnt[w][lc], 1.0f);

        float* rowp = accw + lc * DIM + sub * 4;
        #pragma unroll
        for (int k = 0; k < 8; k++) {
            if (g == k && valid) {
                float4* r4 = (float4*)rowp;
                float4 o = *r4;
                o.x += u.x; o.y += u.y; o.z += u.z; o.w += u.w;
                *r4 = o;
            }
            __builtin_amdgcn_sched_barrier(0);  // keep the 8 steps distinct & ordered
        }

        l_cur = l_nxt;
        v_cur = v_nxt;
    }
    __syncthreads();

    float* gs = ws + WS_SUMS + b * NCAT * DIM;
    const float* sa = (const float*)s_acc;
    for (int i = t; i < NCAT * DIM; i += 256) {
        float val = sa[i] + sa[NCAT * DIM + i] +
                    sa[2 * NCAT * DIM + i] + sa[3 * NCAT * DIM + i];
        if (val != 0.f) unsafeAtomicAdd(&gs[i], val);
    }
    if (t < NCAT) {
        float c = s_cnt[0][t] + s_cnt[1][t] + s_cnt[2][t] + s_cnt[3][t];
        if (c != 0.f) unsafeAtomicAdd(ws + WS_CNTS + b * NCAT + t, c);
    }
}

// One block per batch: normalize sums -> prototypes (padded layout) in global ws.
__global__ __launch_bounds__(256) void k_proto(float* __restrict__ ws) {
    const int b = blockIdx.x;
    const float* gs = ws + WS_SUMS + b * NCAT * DIM;
    const float* gc = ws + WS_CNTS + b * NCAT;
    float* gp = ws + WS_PROT + b * NCATP * DIM;
    float* gpr = ws + WS_PRES + b * NCATP;
    const int dd = threadIdx.x & 31;
    const int r0 = threadIdx.x >> 5;
    for (int c = r0; c < NCAT; c += 8) {
        float cnt = gc[c];
        float val = gs[c * DIM + dd] / fmaxf(cnt, 1.0f);
        float ss = val * val;
        #pragma unroll
        for (int m = 16; m >= 1; m >>= 1) ss += __shfl_xor(ss, m);
        float inv = 1.0f / fmaxf(sqrtf(ss), 1e-12f);
        gp[c * DIM + dd] = val * inv;
        if (dd == 0) gpr[c] = (cnt > 0.f && !is_missing(c)) ? 1.0f : 0.0f;
        // rows 72..79 remain zero from the memset -> logits 0, pres 0
    }
}

// k_loss v4 (MFMA).
// R3 diagnosis: fp32 VALU path at ~77% busy is near the practical vector-ALU
// ceiling; the [N x 32][32 x 72] sim matrix belongs on the matrix pipe.
// bf16x3 split (Ahi*Bhi + Alo*Bhi + Ahi*Blo) keeps ~fp32 precision (~2^-16).
// Per wave: 16 points. A-lane: point=lane&15, k=(lane>>4)*8..+8.
// B-lane: cat=lane&15 (+16*tile), same k chunk -> identical-k-permutation
// cancels. C/D: col(cat)=lane&15, row(point)=(lane>>4)*4+reg  [m89-verified].
// Label logit + norm stay exact fp32; log-sum and label sums accumulate
// separately (both full reductions -> layout mismatch irrelevant).
template <int BPB>
__global__ __launch_bounds__(256, 4) void k_loss(const float* __restrict__ emb,
                                                 const int* __restrict__ lab,
                                                 const float* __restrict__ protos,
                                                 const float* __restrict__ pres,
                                                 float* __restrict__ lossout,
                                                 int Nb) {
    __shared__ float s_red[8];
    const int b = blockIdx.x / BPB;
    const int blk = blockIdx.x % BPB;
    const int t = threadIdx.x;
    const int lane = t & 63;
    const int wave = t >> 6;
    const int lid = lane & 15;   // point (A) / category (B,C) index
    const int sub = lane >> 4;   // k-chunk 0..3 (A,B) / row-quad (C)

    const float* pp = protos + b * NCATP * DIM;
    const float* pr = pres + b * NCATP;
    const float* eb = emb + (size_t)b * Nb * DIM;
    const int* lb = lab + (size_t)b * Nb;

    const float LOG2E = 1.4426950408889634f;
    const float LN2 = 0.6931471805599453f;

    // ---- B fragments (prototypes), built once: 5 tiles x (hi,lo) ----
    short8v bhi[5], blo[5];
    float prl[5];
    #pragma unroll
    for (int n = 0; n < 5; n++) {
        const int cat = n * 16 + lid;
        const float4* qk = (const float4*)(pp + cat * DIM + sub * 8);
        float4 q0 = qk[0], q1 = qk[1];
        float qa[8] = {q0.x, q0.y, q0.z, q0.w, q1.x, q1.y, q1.z, q1.w};
        #pragma unroll
        for (int j = 0; j < 8; j++) {
            float hf;
            bhi[n][j] = f2bf_hi(qa[j], &hf);
            blo[n][j] = f2bf(qa[j] - hf);
        }
        prl[n] = pr[cat];
    }

    float lacc = 0.f, dacc = 0.f, kacc = 0.f;

    #pragma unroll 1
    for (int p0 = (blk * 4 + wave) * 16; p0 < Nb; p0 += BPB * 4 * 16) {
        const int pt = p0 + lid;                 // Nb % 16 == 0 for this problem
        const int l = lb[pt];
        const int lc = min(max(l, 0), NCAT - 1);

        const float4* ep = (const float4*)(eb + (size_t)pt * DIM + sub * 8);
        float4 a0 = ep[0], a1 = ep[1];

        // L2 norm over the 4-lane k-group of this point
        float ss = a0.x * a0.x + a0.y * a0.y + a0.z * a0.z + a0.w * a0.w +
                   a1.x * a1.x + a1.y * a1.y + a1.z * a1.z + a1.w * a1.w;
        ss += __shfl_xor(ss, 16);
        ss += __shfl_xor(ss, 32);
        const float sca = (TEMP_INV * LOG2E) / fmaxf(sqrtf(ss), 1e-12f);
        a0.x *= sca; a0.y *= sca; a0.z *= sca; a0.w *= sca;
        a1.x *= sca; a1.y *= sca; a1.z *= sca; a1.w *= sca;

        // label logit, exact fp32 (log2 space)
        const float4* qk = (const float4*)(pp + lc * DIM + sub * 8);
        float4 q0 = qk[0], q1 = qk[1];
        float dl = q0.x * a0.x + q0.y * a0.y + q0.z * a0.z + q0.w * a0.w +
                   q1.x * a1.x + q1.y * a1.y + q1.z * a1.z + q1.w * a1.w;
        dl += __shfl_xor(dl, 16);
        dl += __shfl_xor(dl, 32);

        const bool keep = (l >= 0) && !is_missing(lc);
        const unsigned long long bal = __ballot(keep && (sub == 0)); // bit p = keep_p, p<16

        // A fragments (hi/lo bf16 split of scaled embedding)
        float ea[8] = {a0.x, a0.y, a0.z, a0.w, a1.x, a1.y, a1.z, a1.w};
        short8v ahi, alo;
        #pragma unroll
        for (int j = 0; j < 8; j++) {
            float hf;
            ahi[j] = f2bf_hi(ea[j], &hf);
            alo[j] = f2bf(ea[j] - hf);
        }

        // 5 n-tiles: 3 MFMAs each, then fold exp2 into row-sums
        float s0 = 0.f, s1 = 0.f, s2 = 0.f, s3 = 0.f;
        #pragma unroll
        for (int n = 0; n < 5; n++) {
            f32x4 acc = {0.f, 0.f, 0.f, 0.f};
            acc = __builtin_amdgcn_mfma_f32_16x16x32_bf16(ahi, bhi[n], acc, 0, 0, 0);
            acc = __builtin_amdgcn_mfma_f32_16x16x32_bf16(alo, bhi[n], acc, 0, 0, 0);
            acc = __builtin_amdgcn_mfma_f32_16x16x32_bf16(ahi, blo[n], acc, 0, 0, 0);
            s0 = fmaf(prl[n], __builtin_amdgcn_exp2f(acc[0]), s0);
            s1 = fmaf(prl[n], __builtin_amdgcn_exp2f(acc[1]), s1);
            s2 = fmaf(prl[n], __builtin_amdgcn_exp2f(acc[2]), s2);
            s3 = fmaf(prl[n], __builtin_amdgcn_exp2f(acc[3]), s3);
        }
        // reduce across the 16 category-lanes
        #pragma unroll
        for (int m = 1; m <= 8; m <<= 1) {
            s0 += __shfl_xor(s0, m);
            s1 += __shfl_xor(s1, m);
            s2 += __shfl_xor(s2, m);
            s3 += __shfl_xor(s3, m);
        }
        // rows r = sub*4 + j ; accumulate log2(sum) for kept rows (lid==0 only)
        const int rb = sub * 4;
        float c0 = ((bal >> (rb + 0)) & 1ull) ? __builtin_amdgcn_logf(s0) : 0.f;
        float c1 = ((bal >> (rb + 1)) & 1ull) ? __builtin_amdgcn_logf(s1) : 0.f;
        float c2 = ((bal >> (rb + 2)) & 1ull) ? __builtin_amdgcn_logf(s2) : 0.f;
        float c3 = ((bal >> (rb + 3)) & 1ull) ? __builtin_amdgcn_logf(s3) : 0.f;
        lacc += (lid == 0) ? (c0 + c1 + c2 + c3) : 0.f;
        dacc += (keep && sub == 0) ? dl : 0.f;
        kacc += (keep && sub == 0) ? 1.f : 0.f;
    }

    // wave reduction: v = sum(log2 sums) - sum(label logits), k = kept count
    float v = lacc - dacc;
    #pragma unroll
    for (int m = 32; m >= 1; m >>= 1) {
        v += __shfl_xor(v, m);
        kacc += __shfl_xor(kacc, m);
    }
    if (lane == 0) {
        s_red[wave] = v;
        s_red[4 + wave] = kacc;
    }
    __syncthreads();
    if (t == 0) {
        float a = s_red[0] + s_red[1] + s_red[2] + s_red[3];
        float k = s_red[4] + s_red[5] + s_red[6] + s_red[7];
        unsafeAtomicAdd(lossout + b, LN2 * a);      // WS_LOSS (ln-space)
        unsafeAtomicAdd(lossout + BNUM + b, k);     // WS_KEEP
    }
}

__global__ void k_final(const float* __restrict__ ws, float* __restrict__ out) {
    if (threadIdx.x == 0 && blockIdx.x == 0) {
        float s = 0.f;
        for (int b = 0; b < BNUM; b++) {
            float l = ws[WS_LOSS + b];
            float k = ws[WS_KEEP + b];
            s += l / fmaxf(k, 1.0f);
        }
        out[0] = SEG_W * (s / BNUM);
    }
}

extern "C" void kernel_launch(void* const* d_in, const int* in_sizes, int n_in,
                              void* d_out, int out_size, void* d_ws, size_t ws_size,
                              hipStream_t stream) {
    const float* emb = (const float*)d_in[0];
    const int* lab = (const int*)d_in[1];
    float* ws = (float*)d_ws;
    float* out = (float*)d_out;
    const int total_pts = in_sizes[1];
    const int Nb = total_pts / BNUM;

    hipMemsetAsync(d_ws, 0, WS_TOTAL * sizeof(float), stream);
    constexpr int BPB_ACC = 256;   // 1024 blocks -> 4 blocks/CU (LDS 38KB/block caps at 4)
    constexpr int BPB_LOSS = 512;  // 2048 blocks
    k_accum<BPB_ACC><<<dim3(BNUM * BPB_ACC), dim3(256), 0, stream>>>(emb, lab, ws, Nb);
    k_proto<<<dim3(BNUM), dim3(256), 0, stream>>>(ws);
    k_loss<BPB_LOSS><<<dim3(BNUM * BPB_LOSS), dim3(256), 0, stream>>>(
        emb, lab, ws + WS_PROT, ws + WS_PRES, ws + WS_LOSS, Nb);
    k_final<<<1, 64, 0, stream>>>(ws, out);
}

// Round 5
// 136.480 us; speedup vs baseline: 2.5435x; 1.1169x over previous
//
#include <hip/hip_runtime.h>
#include <hip/hip_bf16.h>

#define NCAT 72
#define NCATP 80          // padded to 5 MFMA m-tiles of 16
#define DIM 32
#define BNUM 4
#define TEMP_INV (1.0f / 0.07f)
#define SEG_W 10.0f

// ws layout (floats):
#define WS_SUMS 0         // [4][72][32]
#define WS_CNTS 9216      // [4][72]
#define WS_PROT 9504      // [4][80][32]  normalized prototypes, PADDED, absent/missing rows ZERO
#define WS_NABS 19744     // [4]          count of zero rows (exp2 contributes exactly 1 each)
#define WS_LOSS 19748     // [4]
#define WS_KEEP 19752     // [4]
#define WS_TOTAL 19756

typedef __attribute__((ext_vector_type(8))) short short8v;   // 8 bf16
typedef __attribute__((ext_vector_type(4))) float f32x4;

__device__ __forceinline__ bool is_missing(int c) {
    return (c == 13) | (c == 53) | (c == 61);
}

// float -> bf16(RNE) bits, and the fp32 value of that bf16 (for lo-split)
__device__ __forceinline__ short f2bf_hi(float f, float* hi_f) {
    unsigned u = __float_as_uint(f);
    unsigned r = u + 0x7FFFu + ((u >> 16) & 1u);
    *hi_f = __uint_as_float(r & 0xFFFF0000u);
    return (short)(r >> 16);
}
__device__ __forceinline__ short f2bf(float f) {
    unsigned u = __float_as_uint(f);
    unsigned r = u + 0x7FFFu + ((u >> 16) & 1u);
    return (short)(r >> 16);
}

// k_accum v2 (R1: LDS-atomic serialization fixed).
template <int BPB>
__global__ __launch_bounds__(256) void k_accum(const float* __restrict__ emb,
                                               const int* __restrict__ lab,
                                               float* __restrict__ ws, int Nb) {
    __shared__ float s_acc[4][NCAT][DIM];  // per-wave private, rows 128B-aligned
    __shared__ float s_cnt[4][NCAT];
    const int t = threadIdx.x;
    const int b = blockIdx.x / BPB;
    const int blk = blockIdx.x % BPB;
    const int w = t >> 6;         // wave 0..3
    const int g = (t >> 3) & 7;   // point-slot within wave
    const int sub = t & 7;        // float4 index within point
    const int pofs = t >> 3;      // 0..31: point slot within block

    for (int i = t; i < 4 * NCAT * DIM; i += 256) ((float*)s_acc)[i] = 0.f;
    for (int i = t; i < 4 * NCAT; i += 256) ((float*)s_cnt)[i] = 0.f;
    __syncthreads();

    float* accw = &s_acc[w][0][0];
    const float* eb = emb + (size_t)b * Nb * DIM;
    const int* lb = lab + (size_t)b * Nb;

    int p = blk * 32 + pofs;
    int l_cur = lb[p];
    float4 v_cur = ((const float4*)(eb + (size_t)p * DIM))[sub];

    for (int p0 = blk * 32; p0 < Nb; p0 += BPB * 32) {
        const int pn = p0 + BPB * 32 + pofs;
        int l_nxt = -1;
        float4 v_nxt = make_float4(0.f, 0.f, 0.f, 0.f);
        if (pn < Nb) {
            l_nxt = lb[pn];
            v_nxt = ((const float4*)(eb + (size_t)pn * DIM))[sub];
        }

        float ss = v_cur.x * v_cur.x + v_cur.y * v_cur.y +
                   v_cur.z * v_cur.z + v_cur.w * v_cur.w;
        ss += __shfl_xor(ss, 1);
        ss += __shfl_xor(ss, 2);
        ss += __shfl_xor(ss, 4);
        const float inv = 1.0f / fmaxf(sqrtf(ss), 1e-12f);
        const bool valid = (l_cur >= 0);
        const int lc = min(max(l_cur, 0), NCAT - 1);
        float4 u;
        u.x = v_cur.x * inv; u.y = v_cur.y * inv;
        u.z = v_cur.z * inv; u.w = v_cur.w * inv;

        if (valid && sub == 0) unsafeAtomicAdd(&s_cnt[w][lc], 1.0f);

        float* rowp = accw + lc * DIM + sub * 4;
        #pragma unroll
        for (int k = 0; k < 8; k++) {
            if (g == k && valid) {
                float4* r4 = (float4*)rowp;
                float4 o = *r4;
                o.x += u.x; o.y += u.y; o.z += u.z; o.w += u.w;
                *r4 = o;
            }
            __builtin_amdgcn_sched_barrier(0);  // keep the 8 steps distinct & ordered
        }

        l_cur = l_nxt;
        v_cur = v_nxt;
    }
    __syncthreads();

    float* gs = ws + WS_SUMS + b * NCAT * DIM;
    const float* sa = (const float*)s_acc;
    for (int i = t; i < NCAT * DIM; i += 256) {
        float val = sa[i] + sa[NCAT * DIM + i] +
                    sa[2 * NCAT * DIM + i] + sa[3 * NCAT * DIM + i];
        if (val != 0.f) unsafeAtomicAdd(&gs[i], val);
    }
    if (t < NCAT) {
        float c = s_cnt[0][t] + s_cnt[1][t] + s_cnt[2][t] + s_cnt[3][t];
        if (c != 0.f) unsafeAtomicAdd(ws + WS_CNTS + b * NCAT + t, c);
    }
}

// One block per batch: normalize sums -> prototypes (padded, absent rows ZERO)
// and store n_absent = count of zero rows (incl. 8 pad rows).
__global__ __launch_bounds__(256) void k_proto(float* __restrict__ ws) {
    const int b = blockIdx.x;
    __shared__ float s_np;
    if (threadIdx.x == 0) s_np = 0.f;
    __syncthreads();
    const float* gs = ws + WS_SUMS + b * NCAT * DIM;
    const float* gc = ws + WS_CNTS + b * NCAT;
    float* gp = ws + WS_PROT + b * NCATP * DIM;
    const int dd = threadIdx.x & 31;
    const int r0 = threadIdx.x >> 5;
    for (int c = r0; c < NCAT; c += 8) {
        float cnt = gc[c];
        float val = gs[c * DIM + dd] / fmaxf(cnt, 1.0f);
        float ss = val * val;
        #pragma unroll
        for (int m = 16; m >= 1; m >>= 1) ss += __shfl_xor(ss, m);
        float inv = 1.0f / fmaxf(sqrtf(ss), 1e-12f);
        const bool present = (cnt > 0.f) && !is_missing(c);
        gp[c * DIM + dd] = present ? val * inv : 0.f;  // zero row -> exp2 term exactly 1
        if (dd == 0) unsafeAtomicAdd(&s_np, present ? 1.f : 0.f);
        // rows 72..79 remain zero from the memset
    }
    __syncthreads();
    if (threadIdx.x == 0) ws[WS_NABS + b] = (float)NCATP - s_np;
}

// One 16-point group: load, normalize, label-dot (exact fp32), bf16x3 MFMA
// against the wave-resident prototype fragments, softmax-sum, accumulate.
__device__ __forceinline__ void point_group(
    int pt, const float* __restrict__ eb, const int* __restrict__ lb,
    const float* __restrict__ pp, const short8v phi[5], const short8v plo[5],
    float nabs, int sub, float& lacc, float& kacc)
{
    const float LOG2E = 1.4426950408889634f;
    const int l = lb[pt];
    const int lc = min(max(l, 0), NCAT - 1);

    const float4* ep = (const float4*)(eb + (size_t)pt * DIM + sub * 8);
    float4 a0 = ep[0], a1 = ep[1];

    float ss = a0.x * a0.x + a0.y * a0.y + a0.z * a0.z + a0.w * a0.w +
               a1.x * a1.x + a1.y * a1.y + a1.z * a1.z + a1.w * a1.w;
    ss += __shfl_xor(ss, 16);
    ss += __shfl_xor(ss, 32);
    const float sca = (TEMP_INV * LOG2E) / fmaxf(sqrtf(ss), 1e-12f);
    a0.x *= sca; a0.y *= sca; a0.z *= sca; a0.w *= sca;
    a1.x *= sca; a1.y *= sca; a1.z *= sca; a1.w *= sca;

    // label logit (log2 units), exact fp32
    const float4* qk = (const float4*)(pp + lc * DIM + sub * 8);
    float4 q0 = qk[0], q1 = qk[1];
    float dl = q0.x * a0.x + q0.y * a0.y + q0.z * a0.z + q0.w * a0.w +
               q1.x * a1.x + q1.y * a1.y + q1.z * a1.z + q1.w * a1.w;
    dl += __shfl_xor(dl, 16);
    dl += __shfl_xor(dl, 32);

    const bool keep = (l >= 0) && !is_missing(lc);

    // bf16 hi/lo split of the scaled point (B fragment: col=lane&15=point)
    float ea[8] = {a0.x, a0.y, a0.z, a0.w, a1.x, a1.y, a1.z, a1.w};
    short8v ehi, elo;
    #pragma unroll
    for (int j = 0; j < 8; j++) {
        float hf;
        ehi[j] = f2bf_hi(ea[j], &hf);
        elo[j] = f2bf(ea[j] - hf);
    }

    // 5 cat-tiles: C col=point(lane&15), row=cat-in-tile=(sub*4+reg)
    float s = 0.f;
    #pragma unroll
    for (int n = 0; n < 5; n++) {
        f32x4 acc = {0.f, 0.f, 0.f, 0.f};
        acc = __builtin_amdgcn_mfma_f32_16x16x32_bf16(phi[n], ehi, acc, 0, 0, 0);
        acc = __builtin_amdgcn_mfma_f32_16x16x32_bf16(plo[n], ehi, acc, 0, 0, 0);
        acc = __builtin_amdgcn_mfma_f32_16x16x32_bf16(phi[n], elo, acc, 0, 0, 0);
        s += __builtin_amdgcn_exp2f(acc[0]) + __builtin_amdgcn_exp2f(acc[1]) +
             __builtin_amdgcn_exp2f(acc[2]) + __builtin_amdgcn_exp2f(acc[3]);
    }
    // full 80-cat sum for point (lane&15): reduce over the 4 sub-groups
    s += __shfl_xor(s, 16);
    s += __shfl_xor(s, 32);
    s -= nabs;                       // remove the exactly-1 terms of zero rows
    const float cl = __builtin_amdgcn_logf(s);   // log2
    if (keep && sub == 0) {
        lacc += cl - dl;
        kacc += 1.f;
    }
}

// k_loss v5 (swapped operands + 2-way ILP).
// R4 diagnosis: latency-bound (Mfma 7.5%, VALU 37%, HBM 11%, occ 32%) --
// long serial chain + 16-shuffle epilogue + 1 group in flight. Fixes:
// A=protos (built once), B=points -> epilogue is 2 shuffles; pres[] folded
// into zero proto rows + scalar n_absent; two independent 16-pt groups per
// iteration; BPB 512->256 so the proto-fragment prologue amortizes over 8 iters.
template <int BPB>
__global__ __launch_bounds__(256, 4) void k_loss(const float* __restrict__ emb,
                                                 const int* __restrict__ lab,
                                                 const float* __restrict__ protos,
                                                 const float* __restrict__ nabsp,
                                                 float* __restrict__ lossout,
                                                 int Nb) {
    __shared__ float s_red[8];
    const int b = blockIdx.x / BPB;
    const int blk = blockIdx.x % BPB;
    const int t = threadIdx.x;
    const int lane = t & 63;
    const int wave = t >> 6;
    const int lid = lane & 15;   // A: cat-in-tile / B: point / C: point col
    const int sub = lane >> 4;   // k-chunk (A,B) / cat row-quad (C)

    const float* pp = protos + b * NCATP * DIM;
    const float nabs = nabsp[b];
    const float* eb = emb + (size_t)b * Nb * DIM;
    const int* lb = lab + (size_t)b * Nb;
    const float LN2 = 0.6931471805599453f;

    // ---- A fragments (prototypes), built once: 5 tiles x (hi,lo) ----
    short8v phi[5], plo[5];
    #pragma unroll
    for (int n = 0; n < 5; n++) {
        const int cat = n * 16 + lid;
        const float4* qk = (const float4*)(pp + cat * DIM + sub * 8);
        float4 q0 = qk[0], q1 = qk[1];
        float qa[8] = {q0.x, q0.y, q0.z, q0.w, q1.x, q1.y, q1.z, q1.w};
        #pragma unroll
        for (int j = 0; j < 8; j++) {
            float hf;
            phi[n][j] = f2bf_hi(qa[j], &hf);
            plo[n][j] = f2bf(qa[j] - hf);
        }
    }

    float lacc = 0.f, kacc = 0.f;

    #pragma unroll 1
    for (int p0 = (blk * 4 + wave) * 32; p0 < Nb; p0 += BPB * 4 * 32) {
        point_group(p0 + lid,      eb, lb, pp, phi, plo, nabs, sub, lacc, kacc);
        point_group(p0 + 16 + lid, eb, lb, pp, phi, plo, nabs, sub, lacc, kacc);
    }

    #pragma unroll
    for (int m = 32; m >= 1; m >>= 1) {
        lacc += __shfl_xor(lacc, m);
        kacc += __shfl_xor(kacc, m);
    }
    if (lane == 0) {
        s_red[wave] = lacc;
        s_red[4 + wave] = kacc;
    }
    __syncthreads();
    if (t == 0) {
        float a = s_red[0] + s_red[1] + s_red[2] + s_red[3];
        float k = s_red[4] + s_red[5] + s_red[6] + s_red[7];
        unsafeAtomicAdd(lossout + b, LN2 * a);      // WS_LOSS (ln-space)
        unsafeAtomicAdd(lossout + BNUM + b, k);     // WS_KEEP
    }
}

__global__ void k_final(const float* __restrict__ ws, float* __restrict__ out) {
    if (threadIdx.x == 0 && blockIdx.x == 0) {
        float s = 0.f;
        for (int b = 0; b < BNUM; b++) {
            float l = ws[WS_LOSS + b];
            float k = ws[WS_KEEP + b];
            s += l / fmaxf(k, 1.0f);
        }
        out[0] = SEG_W * (s / BNUM);
    }
}

extern "C" void kernel_launch(void* const* d_in, const int* in_sizes, int n_in,
                              void* d_out, int out_size, void* d_ws, size_t ws_size,
                              hipStream_t stream) {
    const float* emb = (const float*)d_in[0];
    const int* lab = (const int*)d_in[1];
    float* ws = (float*)d_ws;
    float* out = (float*)d_out;
    const int total_pts = in_sizes[1];
    const int Nb = total_pts / BNUM;

    hipMemsetAsync(d_ws, 0, WS_TOTAL * sizeof(float), stream);
    constexpr int BPB_ACC = 256;   // 1024 blocks -> 4 blocks/CU (LDS 38KB/block caps at 4)
    constexpr int BPB_LOSS = 256;  // 1024 blocks, 8 iters/wave of 2x16 points
    k_accum<BPB_ACC><<<dim3(BNUM * BPB_ACC), dim3(256), 0, stream>>>(emb, lab, ws, Nb);
    k_proto<<<dim3(BNUM), dim3(256), 0, stream>>>(ws);
    k_loss<BPB_LOSS><<<dim3(BNUM * BPB_LOSS), dim3(256), 0, stream>>>(
        emb, lab, ws + WS_PROT, ws + WS_NABS, ws + WS_LOSS, Nb);
    k_final<<<1, 64, 0, stream>>>(ws, out);
}